// Round 3
// baseline (203.032 us; speedup 1.0000x reference)
//
#include <hip/hip_runtime.h>
#include <hip/hip_bf16.h>

#define NUM_TABLES 16
#define ROWS 200000
#define DIM 64
#define LOOKUPS 131072  // == 2^17

typedef float f32x4 __attribute__((ext_vector_type(4)));

// Each lookup row is DIM=64 floats = 16 float4s. One "slot" = one float4.
// Total slots = NUM_TABLES * LOOKUPS * 16 = 33,554,432.
// grid 2048 x block 256 = 524,288 threads -> exactly 64 grid-stride trips.
__global__ void grouped_embedding_gather(const int* __restrict__ indices,
                                         const float* __restrict__ weights,
                                         float* __restrict__ out) {
    const long long total_slots = (long long)NUM_TABLES * LOOKUPS * (DIM / 4);
    const long long stride = (long long)gridDim.x * blockDim.x;
    long long s = (long long)blockIdx.x * blockDim.x + threadIdx.x;
#pragma unroll 4
    for (; s < total_slots; s += stride) {
        const long long lookup = s >> 4;          // which (table, pos)
        const int slot = (int)(s & 15);           // float4 index within row
        const int table = (int)(lookup >> 17);    // LOOKUPS == 2^17
        const int idx = indices[lookup];          // gather index into table
        const f32x4* __restrict__ src = reinterpret_cast<const f32x4*>(
            weights + (size_t)table * ((size_t)ROWS * DIM) + (size_t)idx * DIM);
        const f32x4 v = src[slot];
        // Output is written once, never re-read: nontemporal store keeps L3
        // capacity for the weight tables (duplicate-index re-hits).
        f32x4* dst = reinterpret_cast<f32x4*>(out + (size_t)lookup * DIM) + slot;
        __builtin_nontemporal_store(v, dst);
    }
}

extern "C" void kernel_launch(void* const* d_in, const int* in_sizes, int n_in,
                              void* d_out, int out_size, void* d_ws, size_t ws_size,
                              hipStream_t stream) {
    const int* indices = (const int*)d_in[0];
    const float* weights = (const float*)d_in[1];
    float* out = (float*)d_out;

    const int block = 256;
    const long long total_slots = (long long)NUM_TABLES * LOOKUPS * (DIM / 4);
    long long blocks_needed = (total_slots + block - 1) / block;
    int grid = (int)((blocks_needed < 2048) ? blocks_needed : 2048);

    grouped_embedding_gather<<<grid, block, 0, stream>>>(indices, weights, out);
}